// Round 11
// baseline (291.421 us; speedup 1.0000x reference)
//
#include <hip/hip_runtime.h>
#include <hip/hip_bf16.h>
#include <float.h>

// Problem constants (from setup_inputs): B=16, N=21504, C=80, G=64, K=9
#define BB 16
#define NN 21504
#define CC 80
#define GG 64
#define KK 9
#define NSEG 4
#define SEG4 (NN / 2 / NSEG)   // float4s per segment: 2688
#define T4   (SEG4 / 64)       // 42 float4 iterations per lane (6 x 7)

// ---------------- focal helpers ----------------
__device__ __forceinline__ float focal_t0(float x) {
    float ax = fabsf(x);
    float em = __expf(-ax);
    float sp = __logf(1.0f + em);
    float spx = fmaxf(x, 0.0f) + sp;     // softplus(x)
    float r = 1.0f / (1.0f + em);
    float p = (x >= 0.0f) ? r : em * r;  // sigmoid(x)
    return 0.75f * spx * p * p;
}

__device__ __forceinline__ float focal_corr(float x) {
    float ax = fabsf(x);
    float em = __expf(-ax);
    float sp = __logf(1.0f + em);
    float spx = fmaxf(x, 0.0f) + sp;
    float spn = fmaxf(-x, 0.0f) + sp;
    float r = 1.0f / (1.0f + em);
    float p = (x >= 0.0f) ? r : em * r;
    float q = 1.0f - p;
    float f1 = 0.25f * spn * q * q;
    float f0 = 0.75f * spx * p * p;
    return f1 - f0;
}

__device__ __forceinline__ float d2f(float cx, float cy, float x, float y) {
    float dx = cx - x, dy = cy - y;
    return dx * dx + dy * dy;
}

// ---------------- Kernel 1: fused top-9 + bbox ----------------
// One block per (b,g) pair; 4 waves = 4 disjoint segments.
// Per wave: branchless per-lane sorted top-9 (named scalars, exact, no
// threshold/rescan/fallback) -> 9 lex-min butterfly extraction rounds ->
// segment top-9 into LDS. __syncthreads. Wave 0 merges 36 -> global top-9,
// writes sel + per-pair l1/gio (plain stores). Block 0 zeroes the 16B
// header (acc0 + ticket) for dispatch 2 — safe: nothing here reads it.

// bubble stage: if (dh < dl) swap both (strict < keeps equal-d stable,
// which preserves lex (d, n) order since inserts arrive in increasing n)
#define BUB(dh, mh, dl, ml)                                      \
    { bool s_ = (dh) < (dl);                                     \
      float f_ = s_ ? (dl) : (dh); (dl) = s_ ? (dh) : (dl); (dh) = f_; \
      int   i_ = s_ ? (ml) : (mh); (ml) = s_ ? (mh) : (ml); (mh) = i_; }

#define INS(dd, nn)                                              \
    { bool c_ = (dd) < e8;                                       \
      e8 = c_ ? (dd) : e8; m8 = c_ ? (nn) : m8;                  \
      BUB(e8, m8, e7, m7); BUB(e7, m7, e6, m6);                  \
      BUB(e6, m6, e5, m5); BUB(e5, m5, e4, m4);                  \
      BUB(e4, m4, e3, m3); BUB(e3, m3, e2, m2);                  \
      BUB(e2, m2, e1, m1); BUB(e1, m1, e0, m0); }

__global__ __launch_bounds__(256) void topk_kernel(
    const float* __restrict__ locations,   // (N,2)
    const float* __restrict__ pred_boxes,  // (B,N,4)
    const float* __restrict__ gt_boxes,    // (B,G,4)
    int*   __restrict__ sel,               // (1024*9)
    float* __restrict__ pair_l1,           // (1024)
    float* __restrict__ pair_gio,          // (1024)
    unsigned long long* __restrict__ hdr)  // 16B: acc0 double + ticket int
{
    if (blockIdx.x == 0 && threadIdx.x < 2) hdr[threadIdx.x] = 0ull;

    int wv   = threadIdx.x >> 6;           // segment 0..3
    int lane = threadIdx.x & 63;
    int pair = blockIdx.x;                 // 0..1023
    int b = pair >> 6;
    int g = pair & (GG - 1);

    __shared__ float ldsD[NSEG * KK];
    __shared__ int   ldsN[NSEG * KK];

    const float4 gt = ((const float4*)gt_boxes)[b * GG + g];
    float cx = gt.x, cy = gt.y;
    const float4* loc4 = (const float4*)locations;
    int base4 = wv * SEG4 + lane;

    // per-lane sorted top-9 in named scalars (e0 smallest ... e8 largest)
    float e0 = FLT_MAX, e1 = FLT_MAX, e2 = FLT_MAX, e3 = FLT_MAX, e4 = FLT_MAX,
          e5 = FLT_MAX, e6 = FLT_MAX, e7 = FLT_MAX, e8 = FLT_MAX;
    int m0 = 0x7fffffff, m1 = 0x7fffffff, m2 = 0x7fffffff, m3 = 0x7fffffff,
        m4 = 0x7fffffff, m5 = 0x7fffffff, m6 = 0x7fffffff, m7 = 0x7fffffff,
        m8 = 0x7fffffff;

    for (int t = 0; t < T4; t += 7) {
        float4 L0 = loc4[base4 + (t + 0) * 64];
        float4 L1 = loc4[base4 + (t + 1) * 64];
        float4 L2 = loc4[base4 + (t + 2) * 64];
        float4 L3 = loc4[base4 + (t + 3) * 64];
        float4 L4 = loc4[base4 + (t + 4) * 64];
        float4 L5 = loc4[base4 + (t + 5) * 64];
        float4 L6 = loc4[base4 + (t + 6) * 64];
        int i0 = base4 + (t + 0) * 64;
        int i1 = base4 + (t + 1) * 64;
        int i2 = base4 + (t + 2) * 64;
        int i3 = base4 + (t + 3) * 64;
        int i4_ = base4 + (t + 4) * 64;
        int i5 = base4 + (t + 5) * 64;
        int i6 = base4 + (t + 6) * 64;
        float da, db;
        da = d2f(cx, cy, L0.x, L0.y); db = d2f(cx, cy, L0.z, L0.w);
        INS(da, 2 * i0); INS(db, 2 * i0 + 1);
        da = d2f(cx, cy, L1.x, L1.y); db = d2f(cx, cy, L1.z, L1.w);
        INS(da, 2 * i1); INS(db, 2 * i1 + 1);
        da = d2f(cx, cy, L2.x, L2.y); db = d2f(cx, cy, L2.z, L2.w);
        INS(da, 2 * i2); INS(db, 2 * i2 + 1);
        da = d2f(cx, cy, L3.x, L3.y); db = d2f(cx, cy, L3.z, L3.w);
        INS(da, 2 * i3); INS(db, 2 * i3 + 1);
        da = d2f(cx, cy, L4.x, L4.y); db = d2f(cx, cy, L4.z, L4.w);
        INS(da, 2 * i4_); INS(db, 2 * i4_ + 1);
        da = d2f(cx, cy, L5.x, L5.y); db = d2f(cx, cy, L5.z, L5.w);
        INS(da, 2 * i5); INS(db, 2 * i5 + 1);
        da = d2f(cx, cy, L6.x, L6.y); db = d2f(cx, cy, L6.z, L6.w);
        INS(da, 2 * i6); INS(db, 2 * i6 + 1);
    }

    // 9 extraction rounds: wave lex-min of each lane's current best (e0,m0)
    for (int r = 0; r < KK; ++r) {
        float bv = e0; int bn = m0;
        for (int s = 1; s < 64; s <<= 1) {
            float ov = __shfl_xor(bv, s);
            int   on = __shfl_xor(bn, s);
            bool cc = (ov < bv) || (ov == bv && on < bn);
            bv = cc ? ov : bv;
            bn = cc ? on : bn;
        }
        bool win = (m0 == bn);             // n unique -> exactly one winner
        e0 = win ? e1 : e0; m0 = win ? m1 : m0;
        e1 = win ? e2 : e1; m1 = win ? m2 : m1;
        e2 = win ? e3 : e2; m2 = win ? m3 : m2;
        e3 = win ? e4 : e3; m3 = win ? m4 : m3;
        e4 = win ? e5 : e4; m4 = win ? m5 : m4;
        e5 = win ? e6 : e5; m5 = win ? m6 : m5;
        e6 = win ? e7 : e6; m6 = win ? m7 : m6;
        e7 = win ? e8 : e7; m7 = win ? m8 : m7;
        e8 = win ? FLT_MAX : e8; m8 = win ? 0x7fffffff : m8;
        if (lane == 0) { ldsD[wv * KK + r] = bv; ldsN[wv * KK + r] = bn; }
    }

    __syncthreads();

    // Wave 0: merge 36 segment candidates, write sel + bbox epilogue
    if (wv == 0) {
        float vd = (lane < NSEG * KK) ? ldsD[lane] : FLT_MAX;
        int   vn = (lane < NSEG * KK) ? ldsN[lane] : 0x7fffffff;

        int myn = 0;
        for (int r = 0; r < KK; ++r) {
            float bv = vd; int bn = vn;
            for (int s = 1; s < 64; s <<= 1) {
                float ov = __shfl_xor(bv, s);
                int   on = __shfl_xor(bn, s);
                bool cc = (ov < bv) || (ov == bv && on < bn);
                bv = cc ? ov : bv;
                bn = cc ? on : bn;
            }
            if (vn == bn) vd = FLT_MAX;
            if (lane == r) myn = bn;
            if (lane == 0) sel[pair * KK + r] = bn;
        }
        myn = myn < 0 ? 0 : (myn >= NN ? NN - 1 : myn);

        float l1 = 0.0f, gio = 0.0f;
        if (lane < KK) {
            float4 p = ((const float4*)pred_boxes)[b * NN + myn];
            l1 = fabsf(p.x - gt.x) + fabsf(p.y - gt.y) + fabsf(p.z - gt.z) + fabsf(p.w - gt.w);

            float ax1 = p.x - 0.5f * p.z, ay1 = p.y - 0.5f * p.w;
            float ax2 = p.x + 0.5f * p.z, ay2 = p.y + 0.5f * p.w;
            float bx1 = gt.x - 0.5f * gt.z, by1 = gt.y - 0.5f * gt.w;
            float bx2 = gt.x + 0.5f * gt.z, by2 = gt.y + 0.5f * gt.w;

            float area_a = (ax2 - ax1) * (ay2 - ay1);
            float area_b = (bx2 - bx1) * (by2 - by1);
            float ix1 = fmaxf(ax1, bx1), iy1 = fmaxf(ay1, by1);
            float ix2 = fminf(ax2, bx2), iy2 = fminf(ay2, by2);
            float iw = fmaxf(ix2 - ix1, 0.0f), ih = fmaxf(iy2 - iy1, 0.0f);
            float inter = iw * ih;
            float uni = area_a + area_b - inter;
            float iou = inter / uni;
            float ccx1 = fminf(ax1, bx1), ccy1 = fminf(ay1, by1);
            float ccx2 = fmaxf(ax2, bx2), ccy2 = fmaxf(ay2, by2);
            float cw = fmaxf(ccx2 - ccx1, 0.0f), ch = fmaxf(ccy2 - ccy1, 0.0f);
            float ac = cw * ch;
            float giou = iou - (ac - uni) / ac;
            gio = 1.0f - giou;
        }
        for (int o = 32; o > 0; o >>= 1) {
            l1 += __shfl_down(l1, o);
            gio += __shfl_down(gio, o);
        }
        if (lane == 0) { pair_l1[pair] = l1; pair_gio[pair] = gio; }
    }
}

// ---------------- Kernel 2: fused focal + correction + finalize ----------
// blocks [0,2048): focal grid-stride slices; blocks [2048,2112): dedup+corr
// (4 per image). Every block fences + tickets; last block reduces the pair
// arrays and writes out[0..2].
#define FOCAL_BLOCKS 2048
#define EPB 144   // corr elements per block (576 / 4)
__global__ __launch_bounds__(256) void focal_corr_kernel(
    const float* __restrict__ logits, const int* __restrict__ sel,
    const int* __restrict__ gt_labels,
    double* __restrict__ acc0, int* __restrict__ ticket,
    const float* __restrict__ pair_l1, const float* __restrict__ pair_gio,
    float* __restrict__ out, int nvec4)
{
    __shared__ double wsum[4];
    __shared__ int keys[GG * KK];
    __shared__ int amlast;

    if (blockIdx.x < FOCAL_BLOCKS) {
        // ---- focal role ----
        const float4* v = (const float4*)logits;
        float s0 = 0.f, s1 = 0.f, s2 = 0.f, s3 = 0.f;
        int stride = FOCAL_BLOCKS * 256;
        for (int i = blockIdx.x * 256 + threadIdx.x; i < nvec4; i += stride) {
            float4 x = v[i];
            s0 += focal_t0(x.x);
            s1 += focal_t0(x.y);
            s2 += focal_t0(x.z);
            s3 += focal_t0(x.w);
        }
        double d = (double)((s0 + s1) + (s2 + s3));
#pragma unroll
        for (int o = 32; o > 0; o >>= 1) d += __shfl_down(d, o);
        if ((threadIdx.x & 63) == 0) wsum[threadIdx.x >> 6] = d;
        __syncthreads();
        if (threadIdx.x == 0) {
            atomicAdd(acc0, wsum[0] + wsum[1] + wsum[2] + wsum[3]);
        }
    } else {
        // ---- correction role ----
        int bq = blockIdx.x - FOCAL_BLOCKS;   // 0..63
        int b  = bq >> 2;
        int q  = bq & 3;

        for (int e = threadIdx.x; e < GG * KK; e += 256) {
            int g = e / KK;
            int n = sel[(b * GG + g) * KK + (e - g * KK)];
            keys[e] = n * CC + gt_labels[b * GG + g];
        }
        __syncthreads();

        bool active = (threadIdx.x < EPB);
        int e = q * EPB + (active ? threadIdx.x : 0);
        int k = keys[e];
        k = active ? k : -1;

        int dup = 0;
        for (int e2 = 0; e2 < GG * KK; e2 += 8) {
            int k0 = keys[e2 + 0];
            int k1 = keys[e2 + 1];
            int k2 = keys[e2 + 2];
            int k3 = keys[e2 + 3];
            int k4 = keys[e2 + 4];
            int k5 = keys[e2 + 5];
            int k6 = keys[e2 + 6];
            int k7 = keys[e2 + 7];
            int h = 0;
            h |= (int)(k0 == k) & (int)(e2 + 0 < e);
            h |= (int)(k1 == k) & (int)(e2 + 1 < e);
            h |= (int)(k2 == k) & (int)(e2 + 2 < e);
            h |= (int)(k3 == k) & (int)(e2 + 3 < e);
            h |= (int)(k4 == k) & (int)(e2 + 4 < e);
            h |= (int)(k5 == k) & (int)(e2 + 5 < e);
            h |= (int)(k6 == k) & (int)(e2 + 6 < e);
            h |= (int)(k7 == k) & (int)(e2 + 7 < e);
            dup |= h;
        }

        float corr = 0.0f;
        if (active && dup == 0) {
            corr = focal_corr(logits[(long long)b * NN * CC + k]);
        }
        double d = (double)corr;
#pragma unroll
        for (int o = 32; o > 0; o >>= 1) d += __shfl_down(d, o);
        if ((threadIdx.x & 63) == 0) wsum[threadIdx.x >> 6] = d;
        __syncthreads();
        if (threadIdx.x == 0) {
            atomicAdd(acc0, wsum[0] + wsum[1] + wsum[2] + wsum[3]);
        }
    }

    // ---- ticket + fused finalize (uniform across roles) ----
    if (threadIdx.x == 0) {
        __threadfence();
        int t = atomicAdd(ticket, 1);
        amlast = (t == (int)gridDim.x - 1) ? 1 : 0;
    }
    __syncthreads();
    if (amlast) {
        double sl = 0.0, sg = 0.0;
        for (int i = threadIdx.x; i < BB * GG; i += 256) {
            sl += (double)pair_l1[i];
            sg += (double)pair_gio[i];
        }
#pragma unroll
        for (int o = 32; o > 0; o >>= 1) {
            sl += __shfl_down(sl, o);
            sg += __shfl_down(sg, o);
        }
        __shared__ double rl[4], rg[4];
        if ((threadIdx.x & 63) == 0) {
            rl[threadIdx.x >> 6] = sl;
            rg[threadIdx.x >> 6] = sg;
        }
        __syncthreads();
        if (threadIdx.x == 0) {
            double a0 = atomicAdd(acc0, 0.0);   // coherent RMW read
            double tl = rl[0] + rl[1] + rl[2] + rl[3];
            double tg = rg[0] + rg[1] + rg[2] + rg[3];
            out[0] = (float)(a0 / (double)((long long)BB * NN * CC));
            out[1] = (float)(tl / (double)(BB * GG * KK * 4));
            out[2] = (float)(tg / (double)(BB * GG * KK));
        }
    }
}

extern "C" void kernel_launch(void* const* d_in, const int* in_sizes, int n_in,
                              void* d_out, int out_size, void* d_ws, size_t ws_size,
                              hipStream_t stream) {
    const float* pred_logits = (const float*)d_in[0];  // (B,N,C)
    const float* pred_boxes  = (const float*)d_in[1];  // (B,N,4)
    const float* locations   = (const float*)d_in[2];  // (N,2)
    const float* gt_boxes    = (const float*)d_in[3];  // (B,G,4)
    const int*   gt_labels   = (const int*)d_in[4];    // (B,G)
    float* out = (float*)d_out;

    // workspace layout
    unsigned long long* hdr = (unsigned long long*)d_ws;   // 16B: acc0+ticket
    double* acc0    = (double*)d_ws;
    int*    ticket  = (int*)((char*)d_ws + 8);
    int*    sel     = (int*)((char*)d_ws + 64);                 // 1024*9 ints
    float*  pair_l1 = (float*)((char*)d_ws + 64 + 36864);       // 1024 floats
    float*  pair_gio= (float*)((char*)d_ws + 64 + 36864 + 4096);

    // 1: fused top-9 + bbox (1024 blocks; block 0 zeroes hdr for dispatch 2)
    topk_kernel<<<BB * GG, 256, 0, stream>>>(
        locations, pred_boxes, gt_boxes, sel, pair_l1, pair_gio, hdr);

    // 2: fused focal + correction + finalize
    int nvec4 = (BB * NN * CC) / 4;
    focal_corr_kernel<<<FOCAL_BLOCKS + BB * 4, 256, 0, stream>>>(
        pred_logits, sel, gt_labels, acc0, ticket, pair_l1, pair_gio, out, nvec4);
}

// Round 12
// 252.140 us; speedup vs baseline: 1.1558x; 1.1558x over previous
//
#include <hip/hip_runtime.h>
#include <hip/hip_bf16.h>
#include <float.h>

// Problem constants (from setup_inputs): B=16, N=21504, C=80, G=64, K=9
#define BB 16
#define NN 21504
#define CC 80
#define GG 64
#define KK 9
#define NSEG 4
#define SEG4 (NN / 2 / NSEG)   // float4s per segment: 2688
#define T4   (SEG4 / 64)       // 42 float4 iterations per lane

// focal grid: 3360 blocks * 256 threads * 8 float4 = 6,881,280 = B*N*C/4 exactly
#define FB 3360
#define FSTRIDE (FB * 256)

// ---------------- focal helpers ----------------
__device__ __forceinline__ float focal_t0(float x) {
    float ax = fabsf(x);
    float em = __expf(-ax);
    float sp = __logf(1.0f + em);
    float spx = fmaxf(x, 0.0f) + sp;     // softplus(x)
    float r = 1.0f / (1.0f + em);
    float p = (x >= 0.0f) ? r : em * r;  // sigmoid(x)
    return 0.75f * spx * p * p;
}

__device__ __forceinline__ float focal_corr(float x) {
    float ax = fabsf(x);
    float em = __expf(-ax);
    float sp = __logf(1.0f + em);
    float spx = fmaxf(x, 0.0f) + sp;
    float spn = fmaxf(-x, 0.0f) + sp;
    float r = 1.0f / (1.0f + em);
    float p = (x >= 0.0f) ? r : em * r;
    float q = 1.0f - p;
    float f1 = 0.25f * spn * q * q;
    float f0 = 0.75f * spx * p * p;
    return f1 - f0;
}

// one shared distance function so both scans produce bit-identical values
__device__ __forceinline__ float d2f(float cx, float cy, float x, float y) {
    float dx = cx - x, dy = cy - y;
    return dx * dx + dy * dy;
}

// Kernel A1: one wave per (pair, segment); block = pair, wave = segment.
// Manual 7-deep load batching. Block 0 zeroes acc + ticket header.
__global__ __launch_bounds__(256) void topk_seg_kernel(
    const float* __restrict__ locations,   // (N,2)
    const float* __restrict__ gt_boxes,    // (B,G,4)
    float* __restrict__ cand_d,            // (1024*NSEG*KK)
    int*   __restrict__ cand_n,
    unsigned long long* __restrict__ hdr)  // 64B header: acc[3] + ticket
{
    if (blockIdx.x == 0 && threadIdx.x < 8) hdr[threadIdx.x] = 0ull;

    int seg  = threadIdx.x >> 6;           // 0..3
    int lane = threadIdx.x & 63;
    int pair = blockIdx.x;                 // 0..1023
    int b = pair >> 6;
    int g = pair & (GG - 1);

    const float4 gt = ((const float4*)gt_boxes)[b * GG + g];
    float cx = gt.x, cy = gt.y;
    const float4* loc4 = (const float4*)locations;
    int base4 = seg * SEG4 + lane;

    // Scan 1: per-lane min over 84 points; 6 groups of 7 batched loads
    float m0 = FLT_MAX, m1 = FLT_MAX, m2 = FLT_MAX, m3 = FLT_MAX;
    for (int t = 0; t < T4; t += 7) {
        float4 L0 = loc4[base4 + (t + 0) * 64];
        float4 L1 = loc4[base4 + (t + 1) * 64];
        float4 L2 = loc4[base4 + (t + 2) * 64];
        float4 L3 = loc4[base4 + (t + 3) * 64];
        float4 L4 = loc4[base4 + (t + 4) * 64];
        float4 L5 = loc4[base4 + (t + 5) * 64];
        float4 L6 = loc4[base4 + (t + 6) * 64];
        m0 = fminf(m0, fminf(d2f(cx, cy, L0.x, L0.y), d2f(cx, cy, L0.z, L0.w)));
        m1 = fminf(m1, fminf(d2f(cx, cy, L1.x, L1.y), d2f(cx, cy, L1.z, L1.w)));
        m2 = fminf(m2, fminf(d2f(cx, cy, L2.x, L2.y), d2f(cx, cy, L2.z, L2.w)));
        m3 = fminf(m3, fminf(d2f(cx, cy, L3.x, L3.y), d2f(cx, cy, L3.z, L3.w)));
        m0 = fminf(m0, fminf(d2f(cx, cy, L4.x, L4.y), d2f(cx, cy, L4.z, L4.w)));
        m1 = fminf(m1, fminf(d2f(cx, cy, L5.x, L5.y), d2f(cx, cy, L5.z, L5.w)));
        m2 = fminf(m2, fminf(d2f(cx, cy, L6.x, L6.y), d2f(cx, cy, L6.z, L6.w)));
    }
    float md = fminf(fminf(m0, m1), fminf(m2, m3));

    // T = 9th-smallest lane-min (ties only enlarge T -> superset, safe)
    float v = md;
    float T = FLT_MAX;
    for (int r = 0; r < KK; ++r) {
        float m = v;
        for (int s = 1; s < 64; s <<= 1) m = fminf(m, __shfl_xor(m, s));
        T = m;
        if (v == m) v = FLT_MAX;
    }

    // Scan 2: collect candidates d2 <= T, up to 6 per lane in named scalars
    float sd0 = FLT_MAX, sd1 = FLT_MAX, sd2 = FLT_MAX,
          sd3 = FLT_MAX, sd4 = FLT_MAX, sd5 = FLT_MAX;
    int   sn0 = 0x7fffffff, sn1 = 0x7fffffff, sn2 = 0x7fffffff,
          sn3 = 0x7fffffff, sn4 = 0x7fffffff, sn5 = 0x7fffffff;
    int cnt = 0;
#define PUSH(dv, nv)                                             \
    do {                                                         \
        if (cnt == 0)      { sd0 = dv; sn0 = nv; }               \
        else if (cnt == 1) { sd1 = dv; sn1 = nv; }               \
        else if (cnt == 2) { sd2 = dv; sn2 = nv; }               \
        else if (cnt == 3) { sd3 = dv; sn3 = nv; }               \
        else if (cnt == 4) { sd4 = dv; sn4 = nv; }               \
        else if (cnt == 5) { sd5 = dv; sn5 = nv; }               \
        ++cnt;                                                   \
    } while (0)
#define TEST(Lv, tt)                                             \
    do {                                                         \
        int i4 = base4 + (tt) * 64;                              \
        float da = d2f(cx, cy, Lv.x, Lv.y);                      \
        float db = d2f(cx, cy, Lv.z, Lv.w);                      \
        if (da <= T) PUSH(da, 2 * i4);                           \
        if (db <= T) PUSH(db, 2 * i4 + 1);                       \
    } while (0)

    for (int t = 0; t < T4; t += 7) {
        float4 L0 = loc4[base4 + (t + 0) * 64];
        float4 L1 = loc4[base4 + (t + 1) * 64];
        float4 L2 = loc4[base4 + (t + 2) * 64];
        float4 L3 = loc4[base4 + (t + 3) * 64];
        float4 L4 = loc4[base4 + (t + 4) * 64];
        float4 L5 = loc4[base4 + (t + 5) * 64];
        float4 L6 = loc4[base4 + (t + 6) * 64];
        TEST(L0, t + 0);
        TEST(L1, t + 1);
        TEST(L2, t + 2);
        TEST(L3, t + 3);
        TEST(L4, t + 4);
        TEST(L5, t + 5);
        TEST(L6, t + 6);
    }
#undef TEST
#undef PUSH

    int ovf = (cnt > 6) ? 1 : 0;
    for (int s = 1; s < 64; s <<= 1) ovf = max(ovf, __shfl_xor(ovf, s));

    int obase = (pair * NSEG + seg) * KK;
    if (ovf == 0) {
        for (int r = 0; r < KK; ++r) {
            float bv = sd0; int bn = sn0;
            bool c;
            c = sd1 < bv; bv = c ? sd1 : bv; bn = c ? sn1 : bn;
            c = sd2 < bv; bv = c ? sd2 : bv; bn = c ? sn2 : bn;
            c = sd3 < bv; bv = c ? sd3 : bv; bn = c ? sn3 : bn;
            c = sd4 < bv; bv = c ? sd4 : bv; bn = c ? sn4 : bn;
            c = sd5 < bv; bv = c ? sd5 : bv; bn = c ? sn5 : bn;
            for (int s = 1; s < 64; s <<= 1) {
                float ov = __shfl_xor(bv, s);
                int   on = __shfl_xor(bn, s);
                bool cc = (ov < bv) || (ov == bv && on < bn);
                bv = cc ? ov : bv;
                bn = cc ? on : bn;
            }
            if (sn0 == bn) sd0 = FLT_MAX;
            if (sn1 == bn) sd1 = FLT_MAX;
            if (sn2 == bn) sd2 = FLT_MAX;
            if (sn3 == bn) sd3 = FLT_MAX;
            if (sn4 == bn) sd4 = FLT_MAX;
            if (sn5 == bn) sd5 = FLT_MAX;
            if (lane == 0) { cand_d[obase + r] = bv; cand_n[obase + r] = bn; }
        }
    } else {
        // rare exact fallback: 9 lex-min rescans of this segment
        float lastD = -1.0f; int lastN = -1;
        for (int r = 0; r < KK; ++r) {
            float bv = FLT_MAX; int bn = 0x7fffffff;
            for (int t = 0; t < T4; ++t) {
                int i4 = base4 + t * 64;
                float4 A = loc4[i4];
                float da = d2f(cx, cy, A.x, A.y);
                float db = d2f(cx, cy, A.z, A.w);
                int na = 2 * i4, nb = 2 * i4 + 1;
                bool ga = (da > lastD) || (da == lastD && na > lastN);
                bool ca = ga && ((da < bv) || (da == bv && na < bn));
                bv = ca ? da : bv; bn = ca ? na : bn;
                bool gb = (db > lastD) || (db == lastD && nb > lastN);
                bool cb = gb && ((db < bv) || (db == bv && nb < bn));
                bv = cb ? db : bv; bn = cb ? nb : bn;
            }
            for (int s = 1; s < 64; s <<= 1) {
                float ov = __shfl_xor(bv, s);
                int   on = __shfl_xor(bn, s);
                bool cc = (ov < bv) || (ov == bv && on < bn);
                bv = cc ? ov : bv;
                bn = cc ? on : bn;
            }
            lastD = bv; lastN = bn;
            if (lane == 0) { cand_d[obase + r] = bv; cand_n[obase + r] = bn; }
        }
    }
}

// Kernel A2: one wave per pair merges 36 candidates (one per lane),
// extracts the global top-9 and does the bbox L1 + GIoU epilogue.
__global__ __launch_bounds__(256) void topk_merge_kernel(
    const float* __restrict__ pred_boxes,  // (B,N,4)
    const float* __restrict__ gt_boxes,    // (B,G,4)
    const float* __restrict__ cand_d,
    const int*   __restrict__ cand_n,
    double* __restrict__ acc,
    int* __restrict__ sel)
{
    int wv   = threadIdx.x >> 6;
    int lane = threadIdx.x & 63;
    int pair = blockIdx.x * 4 + wv;        // 0..1023
    int b = pair >> 6;
    int g = pair & (GG - 1);

    const float4 gt = ((const float4*)gt_boxes)[b * GG + g];

    float vd = FLT_MAX; int vn = 0x7fffffff;
    if (lane < NSEG * KK) {
        vd = cand_d[pair * NSEG * KK + lane];
        vn = cand_n[pair * NSEG * KK + lane];
    }

    int myn = 0;
    for (int r = 0; r < KK; ++r) {
        float bv = vd; int bn = vn;
        for (int s = 1; s < 64; s <<= 1) {
            float ov = __shfl_xor(bv, s);
            int   on = __shfl_xor(bn, s);
            bool cc = (ov < bv) || (ov == bv && on < bn);
            bv = cc ? ov : bv;
            bn = cc ? on : bn;
        }
        if (vn == bn) vd = FLT_MAX;   // n unique across lanes
        if (lane == r) myn = bn;
        if (lane == 0) sel[pair * KK + r] = bn;
    }
    myn = myn < 0 ? 0 : (myn >= NN ? NN - 1 : myn);  // fault guard

    float l1 = 0.0f, gio = 0.0f;
    if (lane < KK) {
        float4 p = ((const float4*)pred_boxes)[b * NN + myn];
        l1 = fabsf(p.x - gt.x) + fabsf(p.y - gt.y) + fabsf(p.z - gt.z) + fabsf(p.w - gt.w);

        float ax1 = p.x - 0.5f * p.z, ay1 = p.y - 0.5f * p.w;
        float ax2 = p.x + 0.5f * p.z, ay2 = p.y + 0.5f * p.w;
        float bx1 = gt.x - 0.5f * gt.z, by1 = gt.y - 0.5f * gt.w;
        float bx2 = gt.x + 0.5f * gt.z, by2 = gt.y + 0.5f * gt.w;

        float area_a = (ax2 - ax1) * (ay2 - ay1);
        float area_b = (bx2 - bx1) * (by2 - by1);
        float ix1 = fmaxf(ax1, bx1), iy1 = fmaxf(ay1, by1);
        float ix2 = fminf(ax2, bx2), iy2 = fminf(ay2, by2);
        float iw = fmaxf(ix2 - ix1, 0.0f), ih = fmaxf(iy2 - iy1, 0.0f);
        float inter = iw * ih;
        float uni = area_a + area_b - inter;
        float iou = inter / uni;
        float ccx1 = fminf(ax1, bx1), ccy1 = fminf(ay1, by1);
        float ccx2 = fmaxf(ax2, bx2), ccy2 = fmaxf(ay2, by2);
        float cw = fmaxf(ccx2 - ccx1, 0.0f), ch = fmaxf(ccy2 - ccy1, 0.0f);
        float ac = cw * ch;
        float giou = iou - (ac - uni) / ac;
        gio = 1.0f - giou;
    }
    for (int o = 32; o > 0; o >>= 1) {
        l1 += __shfl_down(l1, o);
        gio += __shfl_down(gio, o);
    }
    if (lane == 0) {
        atomicAdd(&acc[1], (double)l1);
        atomicAdd(&acc[2], (double)gio);
    }
}

// Kernel B (v2): focal sum with 8-deep batched loads. 3360 blocks x 256
// threads x 8 float4 = exactly B*N*C/4 — no bounds checks. All 8 loads
// issue into named scalars before any use (8 x 16B in flight per thread).
__global__ __launch_bounds__(256) void focal_main_kernel(
    const float* __restrict__ logits, double* __restrict__ acc)
{
    const float4* v = (const float4*)logits;
    int tid = blockIdx.x * 256 + threadIdx.x;

    float4 L0 = v[tid + 0 * FSTRIDE];
    float4 L1 = v[tid + 1 * FSTRIDE];
    float4 L2 = v[tid + 2 * FSTRIDE];
    float4 L3 = v[tid + 3 * FSTRIDE];
    float4 L4 = v[tid + 4 * FSTRIDE];
    float4 L5 = v[tid + 5 * FSTRIDE];
    float4 L6 = v[tid + 6 * FSTRIDE];
    float4 L7 = v[tid + 7 * FSTRIDE];

    float s0 = 0.f, s1 = 0.f, s2 = 0.f, s3 = 0.f;
    s0 += focal_t0(L0.x); s1 += focal_t0(L0.y); s2 += focal_t0(L0.z); s3 += focal_t0(L0.w);
    s0 += focal_t0(L1.x); s1 += focal_t0(L1.y); s2 += focal_t0(L1.z); s3 += focal_t0(L1.w);
    s0 += focal_t0(L2.x); s1 += focal_t0(L2.y); s2 += focal_t0(L2.z); s3 += focal_t0(L2.w);
    s0 += focal_t0(L3.x); s1 += focal_t0(L3.y); s2 += focal_t0(L3.z); s3 += focal_t0(L3.w);
    s0 += focal_t0(L4.x); s1 += focal_t0(L4.y); s2 += focal_t0(L4.z); s3 += focal_t0(L4.w);
    s0 += focal_t0(L5.x); s1 += focal_t0(L5.y); s2 += focal_t0(L5.z); s3 += focal_t0(L5.w);
    s0 += focal_t0(L6.x); s1 += focal_t0(L6.y); s2 += focal_t0(L6.z); s3 += focal_t0(L6.w);
    s0 += focal_t0(L7.x); s1 += focal_t0(L7.y); s2 += focal_t0(L7.z); s3 += focal_t0(L7.w);

    double d = (double)((s0 + s1) + (s2 + s3));
#pragma unroll
    for (int o = 32; o > 0; o >>= 1) d += __shfl_down(d, o);
    __shared__ double wsum[4];
    if ((threadIdx.x & 63) == 0) wsum[threadIdx.x >> 6] = d;
    __syncthreads();
    if (threadIdx.x == 0) {
        atomicAdd(&acc[0], wsum[0] + wsum[1] + wsum[2] + wsum[3]);
    }
}

// Kernel C (v4): dedup + correction + FUSED finalize via device-atomic ticket.
#define EPB 144   // elements per block (576 / 4)
__global__ __launch_bounds__(256) void correction_kernel(
    const float* __restrict__ logits, const int* __restrict__ sel,
    const int* __restrict__ gt_labels, double* __restrict__ acc,
    int* __restrict__ ticket, float* __restrict__ out)
{
    int bq = blockIdx.x;           // 0..63
    int b  = bq >> 2;              // image
    int q  = bq & 3;               // quarter

    __shared__ int keys[GG * KK];
    for (int e = threadIdx.x; e < GG * KK; e += blockDim.x) {
        int g = e / KK;
        int n = sel[(b * GG + g) * KK + (e - g * KK)];
        keys[e] = n * CC + gt_labels[b * GG + g];
    }
    __syncthreads();

    bool active = (threadIdx.x < EPB);
    int e = q * EPB + (active ? threadIdx.x : 0);   // bounded index
    int k = keys[e];
    k = active ? k : -1;                            // -1 never matches

    // branch-free duplicate test, 8 pipelined LDS reads per group
    int dup = 0;
    for (int e2 = 0; e2 < GG * KK; e2 += 8) {
        int k0 = keys[e2 + 0];
        int k1 = keys[e2 + 1];
        int k2 = keys[e2 + 2];
        int k3 = keys[e2 + 3];
        int k4 = keys[e2 + 4];
        int k5 = keys[e2 + 5];
        int k6 = keys[e2 + 6];
        int k7 = keys[e2 + 7];
        int h = 0;
        h |= (int)(k0 == k) & (int)(e2 + 0 < e);
        h |= (int)(k1 == k) & (int)(e2 + 1 < e);
        h |= (int)(k2 == k) & (int)(e2 + 2 < e);
        h |= (int)(k3 == k) & (int)(e2 + 3 < e);
        h |= (int)(k4 == k) & (int)(e2 + 4 < e);
        h |= (int)(k5 == k) & (int)(e2 + 5 < e);
        h |= (int)(k6 == k) & (int)(e2 + 6 < e);
        h |= (int)(k7 == k) & (int)(e2 + 7 < e);
        dup |= h;
    }

    float corr = 0.0f;
    if (active && dup == 0) {
        corr = focal_corr(logits[(long long)b * NN * CC + k]);
    }

    double d = (double)corr;
#pragma unroll
    for (int o = 32; o > 0; o >>= 1) d += __shfl_down(d, o);
    __shared__ double wsum[4];
    if ((threadIdx.x & 63) == 0) wsum[threadIdx.x >> 6] = d;
    __syncthreads();
    __shared__ int amlast;
    if (threadIdx.x == 0) {
        atomicAdd(&acc[0], wsum[0] + wsum[1] + wsum[2] + wsum[3]);
        __threadfence();                       // my add visible before ticket
        int t = atomicAdd(ticket, 1);
        amlast = (t == (int)gridDim.x - 1) ? 1 : 0;
    }
    __syncthreads();
    if (threadIdx.x == 0 && amlast) {
        double a0 = atomicAdd(&acc[0], 0.0);
        double a1 = atomicAdd(&acc[1], 0.0);
        double a2 = atomicAdd(&acc[2], 0.0);
        out[0] = (float)(a0 / (double)((long long)BB * NN * CC));
        out[1] = (float)(a1 / (double)(BB * GG * KK * 4));
        out[2] = (float)(a2 / (double)(BB * GG * KK));
    }
}

extern "C" void kernel_launch(void* const* d_in, const int* in_sizes, int n_in,
                              void* d_out, int out_size, void* d_ws, size_t ws_size,
                              hipStream_t stream) {
    const float* pred_logits = (const float*)d_in[0];  // (B,N,C)
    const float* pred_boxes  = (const float*)d_in[1];  // (B,N,4)
    const float* locations   = (const float*)d_in[2];  // (N,2)
    const float* gt_boxes    = (const float*)d_in[3];  // (B,G,4)
    const int*   gt_labels   = (const int*)d_in[4];    // (B,G)
    float* out = (float*)d_out;

    // workspace layout: 64B header (acc[3] doubles + ticket int + pad)
    unsigned long long* hdr = (unsigned long long*)d_ws;
    double* acc    = (double*)d_ws;
    int*    ticket = (int*)((char*)d_ws + 24);
    int*    sel    = (int*)((char*)d_ws + 64);                    // 1024*9 ints
    float*  candd  = (float*)((char*)d_ws + 64 + 36864);          // 1024*4*9 floats
    int*    candn  = (int*)((char*)d_ws + 64 + 36864 + 147456);

    // A1: per-segment top-9 (1024 blocks x 4 waves); block 0 zeroes header
    topk_seg_kernel<<<BB * GG, 256, 0, stream>>>(locations, gt_boxes, candd, candn, hdr);

    // A2: merge 36 candidates/pair + bbox epilogue (256 blocks x 4 waves)
    topk_merge_kernel<<<BB * GG / 4, 256, 0, stream>>>(pred_boxes, gt_boxes, candd, candn, acc, sel);

    // B: focal main sum (8-deep batched loads, exact coverage)
    focal_main_kernel<<<FB, 256, 0, stream>>>(pred_logits, acc);

    // C: corrections + fused finalize (4 blocks per image, ticketed)
    correction_kernel<<<BB * 4, 256, 0, stream>>>(pred_logits, sel, gt_labels, acc, ticket, out);
}